// Round 5
// baseline (602.527 us; speedup 1.0000x reference)
//
#include <hip/hip_runtime.h>

// ---------------------------------------------------------------------------
// HierarchicalSparseLayer: top-2 MoE with block-sparse (64x64) masked weights
// B=8192 tokens, D=1024, H=4096, E=16 experts, K=2, + block-sparse cross proj.
// R5: latency-bound fix — BM=128 (48 KB LDS -> 3 blocks/CU), H chunked at
//     2048 so h/y stay L3-resident, setprio around MFMA, balanced wcast.
// ---------------------------------------------------------------------------

#define NTOK 8192
#define DIM  1024
#define HID  4096
#define NEXP 16
#define BM   128
#define ROWS_CAP (NTOK*2 + NEXP*256)   // 20480 (expert regions padded to 256)
#define HC    2048

typedef __attribute__((ext_vector_type(4))) float fx4;
typedef __attribute__((ext_vector_type(4))) unsigned int ux4;
typedef __attribute__((ext_vector_type(2))) unsigned int ux2;
typedef __attribute__((ext_vector_type(8))) short s8v;
union V16 { ux4 u; s8v s; };

__device__ __forceinline__ unsigned int f2bf(float f) {
  unsigned int u = __float_as_uint(f);
  return (u + 0x7fffu + ((u >> 16) & 1u)) >> 16;   // RNE, inputs finite
}

__device__ __forceinline__ unsigned int cvt_pk(float lo, float hi) {
  unsigned int r;
  asm("v_cvt_pk_bf16_f32 %0, %1, %2" : "=v"(r) : "v"(lo), "v"(hi));
  return r;
}

__device__ __forceinline__ bool mask_at(const void* m, int flag, size_t idx) {
  if (flag == 0) return ((const unsigned char*)m)[idx] != 0;
  if (flag == 1) return ((const int*)m)[idx] != 0;
  return ((const float*)m)[idx] != 0.0f;
}

__device__ __forceinline__ int flag_of(int ev) {
  return (ev & 2) ? 2 : ((ev & 1) ? 0 : 1);
}

// --------------------------- mask dtype detection ---------------------------
__global__ void k_detect(const unsigned int* __restrict__ m, int* __restrict__ meta) {
  int bits = 0;
  size_t base = (size_t)blockIdx.x * 4096 + threadIdx.x;
  for (int j = 0; j < 16; j++) {
    unsigned int v = m[base + 256 * j];
    if (v == 0x3f800000u) bits |= 2;
    else if (v > 1u)      bits |= 1;
  }
  if (bits) atomicOr(&meta[1], bits);
}

// --------------------------- routing ---------------------------------------
// meta: [1]=detect bits [8..23]=counts [32..47]=offsets [48]=total
//       [64..79]=slot counters
__global__ void k_route(const float* __restrict__ x,
                        const float* __restrict__ gw,    // gate_w[-1] [16,1024]
                        const float* __restrict__ temp,
                        int* __restrict__ top2i, float* __restrict__ top2w,
                        int* __restrict__ meta)
{
  __shared__ float gwsh[NEXP * DIM];
  for (int i = threadIdx.x; i < NEXP * DIM; i += 256) gwsh[i] = gw[i];
  __syncthreads();

  const int t = blockIdx.x * 4 + (threadIdx.x >> 6);
  const int l = threadIdx.x & 63;
  const float* xr = x + (size_t)t * DIM;
  float xv[16];
  #pragma unroll
  for (int j = 0; j < 16; j++) xv[j] = xr[l + 64 * j];
  float logit[16];
  #pragma unroll
  for (int e = 0; e < 16; e++) {
    const float* g = gwsh + e * DIM;
    float s = 0.f;
    #pragma unroll
    for (int j = 0; j < 16; j++) s += xv[j] * g[l + 64 * j];
    #pragma unroll
    for (int o = 32; o >= 1; o >>= 1) s += __shfl_xor(s, o);
    logit[e] = s;
  }
  if (l == 0) {
    const float tinv = 1.0f / temp[0];
    int i0 = 0; float v0 = logit[0] * tinv;
    #pragma unroll
    for (int e = 1; e < 16; e++) { float v = logit[e] * tinv; if (v > v0) { v0 = v; i0 = e; } }
    int i1 = -1; float v1 = 0.f; bool first = true;
    #pragma unroll
    for (int e = 0; e < 16; e++) {
      if (e == i0) continue;
      float v = logit[e] * tinv;
      if (first || v > v1) { v1 = v; i1 = e; first = false; }
    }
    float ex = expf(v1 - v0);
    float den = 1.0f + ex;
    top2i[2 * t] = i0; top2i[2 * t + 1] = i1;
    top2w[2 * t] = 1.0f / den; top2w[2 * t + 1] = ex / den;
    atomicAdd(&meta[8 + i0], 1);
    atomicAdd(&meta[8 + i1], 1);
  }
}

__global__ void k_offsets(int* __restrict__ meta) {
  if (threadIdx.x == 0 && blockIdx.x == 0) {
    int o = 0;
    for (int e = 0; e < 16; e++) { meta[32 + e] = o; o += (meta[8 + e] + 255) & ~255; }
    meta[48] = o;
  }
}

__global__ void k_assign(const int* __restrict__ top2i,
                         const float* __restrict__ top2w,
                         int* __restrict__ meta, int* __restrict__ tok_of_row,
                         int* __restrict__ t2row)
{
  int t = blockIdx.x * 256 + threadIdx.x;
  if (t >= NTOK) return;
  #pragma unroll
  for (int k = 0; k < 2; k++) {
    int e = top2i[2 * t + k];
    int slot = atomicAdd(&meta[64 + e], 1);
    int row = meta[32 + e] + slot;
    tok_of_row[row] = t;
    t2row[2 * t + k] = row;
  }
}

// --------------------------- block-mask bitmaps ------------------------------
__global__ void k_bmask(const void* __restrict__ m1, const void* __restrict__ m2,
                        const void* __restrict__ mc, const int* __restrict__ meta,
                        unsigned int* __restrict__ bm1,
                        unsigned long long* __restrict__ bm2,
                        unsigned int* __restrict__ bmc)
{
  const int flag = flag_of(meta[1]);
  const int id = blockIdx.x * 256 + threadIdx.x;
  if (id < 1024) {
    int e = id >> 6, ct = id & 63;
    unsigned int bits = 0;
    size_t basei = (size_t)e * DIM * HID + (size_t)ct * 64;
    for (int db = 0; db < 16; db++)
      if (mask_at(m1, flag, basei + (size_t)db * 64 * HID)) bits |= 1u << db;
    bm1[id] = bits;
  }
  if (id < 256) {
    int e = id >> 4, ct = id & 15;
    unsigned long long bits = 0;
    size_t basei = (size_t)e * HID * DIM + (size_t)ct * 64;
    for (int db = 0; db < 64; db++)
      if (mask_at(m2, flag, basei + (size_t)db * 64 * DIM)) bits |= 1ull << db;
    bm2[id] = bits;
  }
  if (id < 16) {
    unsigned int bits = 0;
    for (int db = 0; db < 16; db++)
      if (mask_at(mc, flag, (size_t)db * 64 * DIM + (size_t)id * 64)) bits |= 1u << db;
    bmc[id] = bits;
  }
}

// --------------------------- weight pre-cast (packed swizzled bf16) ---------
// Active 64x64 block -> 8 KB image == the compute loop's LDS B layout:
// ux4 slot (col*8 + (seg ^ (col&7))) holds k = seg*8..seg*8+7 for column col.
__global__ void k_wcast(const float* __restrict__ w1, const float* __restrict__ w2,
                        const float* __restrict__ cw,
                        const unsigned int* __restrict__ bm1,
                        const unsigned long long* __restrict__ bm2,
                        const unsigned int* __restrict__ bmc,
                        unsigned short* __restrict__ w1p,
                        unsigned short* __restrict__ w2p,
                        unsigned short* __restrict__ cwp)
{
  const int gid = blockIdx.x;
  const int tid = threadIdx.x;

  auto pack_block = [&](const float* src0, int kstride, char* dst) {
    #pragma unroll
    for (int r = 0; r < 2; r++) {
      const int item = r * 256 + tid;
      const int col = item & 63, seg = item >> 6;
      const float* sp = src0 + (size_t)(seg * 8) * kstride + col;
      ux4 v;
      #pragma unroll
      for (int j = 0; j < 4; j++)
        v[j] = cvt_pk(sp[(size_t)(2 * j) * kstride], sp[(size_t)(2 * j + 1) * kstride]);
      *(ux4*)(dst + ((size_t)(col * 8 + (seg ^ (col & 7))) << 4)) = v;
    }
  };

  if (gid < 1024) {                    // w1: e = gid>>6, ct = gid&63
    const int e = gid >> 6, ct = gid & 63;
    unsigned int bits = bm1[gid];
    while (bits) {
      const int kb = __ffs(bits) - 1; bits &= bits - 1;
      pack_block(w1 + ((size_t)e * DIM + kb * 64) * HID + ct * 64, HID,
                 (char*)w1p + (((size_t)gid * 16 + kb) << 13));
    }
  } else if (gid < 2048) {             // w2 split in kb-quarters for balance
    const int g2 = gid - 1024;
    const int pair = g2 >> 2, q = g2 & 3;     // pair: e*16+ct
    const int e = pair >> 4, ct = pair & 15;
    unsigned int bits = (unsigned int)((bm2[pair] >> (q * 16)) & 0xFFFFull);
    while (bits) {
      const int kb = (__ffs(bits) - 1) + q * 16; bits &= bits - 1;
      pack_block(w2 + ((size_t)e * HID + kb * 64) * DIM + ct * 64, DIM,
                 (char*)w2p + (((size_t)pair * 64 + kb) << 13));
    }
  } else {                             // cross: ct = gid-2048
    const int ct = gid - 2048;
    unsigned int bits = bmc[ct];
    while (bits) {
      const int kb = __ffs(bits) - 1; bits &= bits - 1;
      pack_block(cw + (size_t)(kb * 64) * DIM + ct * 64, DIM,
                 (char*)cwp + (((size_t)(ct * 16 + kb)) << 13));
    }
  }
}

__global__ void k_xcast(const float* __restrict__ x, unsigned short* __restrict__ xb) {
  int i = blockIdx.x * 256 + threadIdx.x;
  const fx4* s = (const fx4*)x + (size_t)i * 2;
  fx4 a = s[0], b = s[1];
  ux4 o;
  o[0] = cvt_pk(a[0], a[1]);
  o[1] = cvt_pk(a[2], a[3]);
  o[2] = cvt_pk(b[0], b[1]);
  o[3] = cvt_pk(b[2], b[3]);
  ((ux4*)xb)[i] = o;
}

// --------------------------- GEMM 1: h = silu(x @ w1m + b1) -----------------
// BM=128, 4 waves (2x2), dbuf, A+B via global_load_lds. 48.5 KB LDS -> 3/CU.
__global__ __launch_bounds__(256, 3)
void k_gemm1(const unsigned short* __restrict__ xb,
             const unsigned short* __restrict__ w1p, const float* __restrict__ b1,
             const unsigned int* __restrict__ bm1,
             const int* __restrict__ meta, const int* __restrict__ tok_of_row,
             unsigned short* __restrict__ h_c, int c0)
{
  __shared__ ux4 Ash[2][1024];                  // 2 x 16 KB (128 rows x 64 k)
  __shared__ __align__(16) ux2 Bsh[2][1024];    // 2 x 8 KB
  __shared__ int tok_sh[128];

  const int NCT = HC >> 6;                      // 32
  const int rt = blockIdx.x / NCT, ct = blockIdx.x % NCT;
  const int base = rt * BM;
  if (base >= meta[48]) return;
  int e = 0;
  #pragma unroll
  for (int i = 1; i < 16; i++) if (meta[32 + i] <= base) e = i;

  const int tid = threadIdx.x;
  const int wv = tid >> 6;
  const int wr = wv >> 1, wc = wv & 1;
  const int jg0 = c0 + ct * 64;
  const int ctg = jg0 >> 6;
  unsigned int bits = bm1[e * 64 + ctg];

  const unsigned int sseg = (unsigned int)(((tid & 7) ^ ((tid >> 3) & 7)) * 16);
  unsigned int aoff[4];
  #pragma unroll
  for (int i = 0; i < 4; i++) {
    int tok = tok_of_row[base + i * 32 + (tid >> 3)];
    if (tok < 0) tok = 0;
    aoff[i] = (unsigned int)tok * (DIM * 2) + sseg;
  }
  if (tid < 128) tok_sh[tid] = tok_of_row[base + tid];

  const int l = tid & 63, l16 = l & 15, lhi = l >> 4;

  fx4 acc[4][2] = {};

  auto STAGE_A = [&](int b, int d0) {
    const char* gp = (const char*)xb + (d0 << 1);
    #pragma unroll
    for (int i = 0; i < 4; i++)
      __builtin_amdgcn_global_load_lds(
        (const __attribute__((address_space(1))) unsigned int*)(gp + aoff[i]),
        (__attribute__((address_space(3))) unsigned int*)&Ash[b][i * 256 + wv * 64],
        16, 0, 0);
  };
  auto STAGE_B = [&](int b, int kb) {
    const char* src = (const char*)w1p + (((size_t)(e * 64 + ctg) * 16 + kb) << 13) + tid * 16;
    char* dstb = (char*)&Bsh[b][0] + wv * 1024;
    #pragma unroll
    for (int i = 0; i < 2; i++)
      __builtin_amdgcn_global_load_lds(
        (const __attribute__((address_space(1))) unsigned int*)(src + i * 4096),
        (__attribute__((address_space(3))) unsigned int*)(dstb + i * 4096),
        16, 0, 0);
  };
  auto COMPUTE = [&](int b) {
    __builtin_amdgcn_s_setprio(1);
    #pragma unroll
    for (int ks = 0; ks < 2; ks++) {
      s8v a[4], bb[2];
      const int seg = ks * 4 + lhi;
      #pragma unroll
      for (int m = 0; m < 4; m++) {
        const int row = wr * 64 + m * 16 + l16;
        V16 v; v.u = Ash[b][row * 8 + (seg ^ (row & 7))]; a[m] = v.s;
      }
      #pragma unroll
      for (int n = 0; n < 2; n++) {
        const int col = wc * 32 + n * 16 + l16;
        V16 v; v.u = ((const ux4*)&Bsh[b][0])[col * 8 + (seg ^ (col & 7))]; bb[n] = v.s;
      }
      #pragma unroll
      for (int m = 0; m < 4; m++)
        #pragma unroll
        for (int n = 0; n < 2; n++)
          acc[m][n] = __builtin_amdgcn_mfma_f32_16x16x32_bf16(a[m], bb[n], acc[m][n], 0, 0, 0);
    }
    __builtin_amdgcn_s_setprio(0);
  };

  if (bits) {
    int kb = __ffs(bits) - 1; bits &= bits - 1;
    STAGE_A(0, kb << 6); STAGE_B(0, kb);
    __syncthreads();
    int cur = 0;
    for (;;) {
      int nb = -1;
      if (bits) { nb = __ffs(bits) - 1; bits &= bits - 1; }
      if (nb >= 0) { STAGE_A(cur ^ 1, nb << 6); STAGE_B(cur ^ 1, nb); }
      COMPUTE(cur);
      __syncthreads();
      cur ^= 1;
      if (nb < 0) break;
    }
  }

  // epilogue: silu(acc + b1) -> LDS bf16 tile -> coalesced 16B dump
  unsigned short* hs = (unsigned short*)&Ash[0][0];
  __syncthreads();
  #pragma unroll
  for (int m = 0; m < 4; m++)
    #pragma unroll
    for (int n = 0; n < 2; n++) {
      const int gcol = jg0 + wc * 32 + n * 16 + l16;
      const float bbv = b1[e * HID + gcol];
      #pragma unroll
      for (int i = 0; i < 4; i++) {
        const int row = wr * 64 + m * 16 + lhi * 4 + i;
        float v = acc[m][n][i] + bbv;
        float hval = v / (1.0f + expf(-v));
        unsigned short o = (tok_sh[row] >= 0) ? (unsigned short)f2bf(hval) : (unsigned short)0;
        hs[row * 64 + wc * 32 + n * 16 + l16] = o;
      }
    }
  __syncthreads();
  {
    const ux4* s = (const ux4*)hs;
    #pragma unroll
    for (int j = 0; j < 4; j++) {
      const int c2 = j * 256 + tid;
      const int row = c2 >> 3;
      *(ux4*)(h_c + (size_t)(base + row) * HC + ct * 64 + (c2 & 7) * 8) = s[c2];
    }
  }
}

// --------------------------- GEMM 2: y = h @ w2m + b2 (pair rows) -----------
__global__ __launch_bounds__(256, 3)
void k_gemm2(const unsigned short* __restrict__ h_c,
             const unsigned short* __restrict__ w2p, const float* __restrict__ b2,
             const unsigned long long* __restrict__ bm2,
             const int* __restrict__ meta, float* __restrict__ y, int c0)
{
  __shared__ ux4 Ash[2][1024];
  __shared__ __align__(16) ux2 Bsh[2][1024];

  const int NCT = 16;
  const int rt = blockIdx.x / NCT, ct = blockIdx.x % NCT;
  const int base = rt * BM;
  if (base >= meta[48]) return;
  int e = 0;
  #pragma unroll
  for (int i = 1; i < 16; i++) if (meta[32 + i] <= base) e = i;

  const int tid = threadIdx.x;
  const int wv = tid >> 6;
  const int wr = wv >> 1, wc = wv & 1;
  const int jg0 = ct * 64;
  unsigned int bits = (unsigned int)((bm2[e * 16 + ct] >> (c0 >> 6)) & 0xFFFFFFFFull);

  const unsigned int sseg = (unsigned int)(((tid & 7) ^ ((tid >> 3) & 7)) * 16);
  unsigned int aoff[4];
  #pragma unroll
  for (int i = 0; i < 4; i++)
    aoff[i] = (unsigned int)(base + i * 32 + (tid >> 3)) * (unsigned int)(HC * 2) + sseg;

  const int l = tid & 63, l16 = l & 15, lhi = l >> 4;

  fx4 acc[4][2] = {};

  auto STAGE_A = [&](int b, int d0) {
    const char* gp = (const char*)h_c + (d0 << 1);
    #pragma unroll
    for (int i = 0; i < 4; i++)
      __builtin_amdgcn_global_load_lds(
        (const __attribute__((address_space(1))) unsigned int*)(gp + aoff[i]),
        (__attribute__((address_space(3))) unsigned int*)&Ash[b][i * 256 + wv * 64],
        16, 0, 0);
  };
  auto STAGE_B = [&](int b, int kb) {
    const char* src = (const char*)w2p + (((size_t)(e * 16 + ct) * 64 + (kb + (c0 >> 6))) << 13) + tid * 16;
    char* dstb = (char*)&Bsh[b][0] + wv * 1024;
    #pragma unroll
    for (int i = 0; i < 2; i++)
      __builtin_amdgcn_global_load_lds(
        (const __attribute__((address_space(1))) unsigned int*)(src + i * 4096),
        (__attribute__((address_space(3))) unsigned int*)(dstb + i * 4096),
        16, 0, 0);
  };
  auto COMPUTE = [&](int b) {
    __builtin_amdgcn_s_setprio(1);
    #pragma unroll
    for (int ks = 0; ks < 2; ks++) {
      s8v a[4], bb[2];
      const int seg = ks * 4 + lhi;
      #pragma unroll
      for (int m = 0; m < 4; m++) {
        const int row = wr * 64 + m * 16 + l16;
        V16 v; v.u = Ash[b][row * 8 + (seg ^ (row & 7))]; a[m] = v.s;
      }
      #pragma unroll
      for (int n = 0; n < 2; n++) {
        const int col = wc * 32 + n * 16 + l16;
        V16 v; v.u = ((const ux4*)&Bsh[b][0])[col * 8 + (seg ^ (col & 7))]; bb[n] = v.s;
      }
      #pragma unroll
      for (int m = 0; m < 4; m++)
        #pragma unroll
        for (int n = 0; n < 2; n++)
          acc[m][n] = __builtin_amdgcn_mfma_f32_16x16x32_bf16(a[m], bb[n], acc[m][n], 0, 0, 0);
    }
    __builtin_amdgcn_s_setprio(0);
  };

  if (bits) {
    int kb = __ffs(bits) - 1; bits &= bits - 1;
    STAGE_A(0, kb << 6); STAGE_B(0, kb);
    __syncthreads();
    int cur = 0;
    for (;;) {
      int nb = -1;
      if (bits) { nb = __ffs(bits) - 1; bits &= bits - 1; }
      if (nb >= 0) { STAGE_A(cur ^ 1, nb << 6); STAGE_B(cur ^ 1, nb); }
      COMPUTE(cur);
      __syncthreads();
      cur ^= 1;
      if (nb < 0) break;
    }
  }

  #pragma unroll
  for (int m = 0; m < 4; m++)
    #pragma unroll
    for (int n = 0; n < 2; n++) {
      const int gcol = jg0 + wc * 32 + n * 16 + l16;
      const float bbv = b2[e * DIM + gcol];
      #pragma unroll
      for (int i = 0; i < 4; i++) {
        const int row = wr * 64 + m * 16 + lhi * 4 + i;
        float* p = &y[(size_t)(base + row) * DIM + gcol];
        if (c0 == 0) *p = acc[m][n][i] + bbv;
        else         *p += acc[m][n][i];
      }
    }
}

// --------------------------- cross: out = x + eo @ cwm + cb -----------------
__global__ __launch_bounds__(256, 3)
void k_cross(const float* __restrict__ y, const float* __restrict__ x,
             const unsigned short* __restrict__ cwp, const float* __restrict__ cb,
             const unsigned int* __restrict__ bmc,
             const int* __restrict__ t2row, const float* __restrict__ t2w,
             float* __restrict__ out)
{
  __shared__ ux4 Ash[1024];                  // 128 rows x 64 k
  __shared__ __align__(16) ux2 Bsh[1024];

  const int NCT = 16;
  const int rt = blockIdx.x / NCT, ct = blockIdx.x % NCT;
  const int base = rt * BM;
  const int tid = threadIdx.x;
  const int wv = tid >> 6;
  const int wr = wv >> 1, wc = wv & 1;
  const int jg0 = ct * 64;

  const int arow = tid >> 1, sub = tid & 1;
  const int r0 = t2row[2 * (base + arow)], r1 = t2row[2 * (base + arow) + 1];
  const float w0 = t2w[2 * (base + arow)], w1 = t2w[2 * (base + arow) + 1];

  fx4 acc[4][2] = {};
  const int l = tid & 63, l16 = l & 15, lhi = l >> 4;

  unsigned int bits = bmc[ct];
  while (bits) {
    const int kb = __ffs(bits) - 1; bits &= bits - 1;
    const int d0 = kb * 64;
    {   // stage A: combine two pair rows -> bf16 (swizzled ds_write)
      const fx4* s0 = (const fx4*)(y + (size_t)r0 * DIM + d0);
      const fx4* s1 = (const fx4*)(y + (size_t)r1 * DIM + d0);
      #pragma unroll
      for (int s = 0; s < 4; s++) {
        const int seg = sub * 4 + s;
        fx4 p = w0 * s0[seg * 2]     + w1 * s1[seg * 2];
        fx4 q = w0 * s0[seg * 2 + 1] + w1 * s1[seg * 2 + 1];
        ux4 v;
        v[0] = cvt_pk(p[0], p[1]);
        v[1] = cvt_pk(p[2], p[3]);
        v[2] = cvt_pk(q[0], q[1]);
        v[3] = cvt_pk(q[2], q[3]);
        Ash[arow * 8 + (seg ^ (arow & 7))] = v;
      }
    }
    {   // stage B: DMA packed cw block
      const char* src = (const char*)cwp + (((size_t)(ct * 16 + kb)) << 13) + tid * 16;
      char* dstb = (char*)&Bsh[0] + wv * 1024;
      #pragma unroll
      for (int i = 0; i < 2; i++)
        __builtin_amdgcn_global_load_lds(
          (const __attribute__((address_space(1))) unsigned int*)(src + i * 4096),
          (__attribute__((address_space(3))) unsigned int*)(dstb + i * 4096),
          16, 0, 0);
    }
    __syncthreads();
    __builtin_amdgcn_s_setprio(1);
    #pragma unroll
    for (int ks = 0; ks < 2; ks++) {
      s8v a[4], b[2];
      const int seg = ks * 4 + lhi;
      #pragma unroll
      for (int m = 0; m < 4; m++) {
        const int row = wr * 64 + m * 16 + l16;
        V16 v; v.u = Ash[row * 8 + (seg ^ (row & 7))]; a[m] = v.s;
      }
      #pragma unroll
      for (int n = 0; n < 2; n++) {
        const int col = wc * 32 + n * 16 + l16;
        V16 v; v.u = ((const ux4*)Bsh)[col * 8 + (seg ^ (col & 7))]; b[n] = v.s;
      }
      #pragma unroll
      for (int m = 0; m < 4; m++)
        #pragma unroll
        for (int n = 0; n < 2; n++)
          acc[m][n] = __builtin_amdgcn_mfma_f32_16x16x32_bf16(a[m], b[n], acc[m][n], 0, 0, 0);
    }
    __builtin_amdgcn_s_setprio(0);
    __syncthreads();
  }

  #pragma unroll
  for (int m = 0; m < 4; m++)
    #pragma unroll
    for (int n = 0; n < 2; n++) {
      const int gcol = jg0 + wc * 32 + n * 16 + l16;
      #pragma unroll
      for (int i = 0; i < 4; i++) {
        const int row = wr * 64 + m * 16 + lhi * 4 + i;
        const size_t idx = (size_t)(base + row) * DIM + gcol;
        out[idx] = acc[m][n][i] + x[idx] + cb[gcol];
      }
    }
}

// ---------------------------------------------------------------------------
extern "C" void kernel_launch(void* const* d_in, const int* in_sizes, int n_in,
                              void* d_out, int out_size, void* d_ws, size_t ws_size,
                              hipStream_t stream)
{
  (void)in_sizes; (void)n_in; (void)out_size; (void)ws_size;
  const float* x      = (const float*)d_in[0];
  const float* gate_w = (const float*)d_in[1];   // [2,16,1024]
  const float* temp   = (const float*)d_in[2];   // [2]
  const float* w1     = (const float*)d_in[3];   // [16,1024,4096]
  const float* b1     = (const float*)d_in[4];
  const float* w2     = (const float*)d_in[5];   // [16,4096,1024]
  const float* b2     = (const float*)d_in[6];
  const float* cw     = (const float*)d_in[7];   // [1024,1024]
  const float* cb     = (const float*)d_in[8];
  const void*  mask1  = d_in[9];
  const void*  mask2  = d_in[10];
  const void*  cmask  = d_in[11];
  float* out = (float*)d_out;
  char* ws = (char*)d_ws;

  size_t off = 0;
  auto walloc = [&](size_t b) { size_t r = off; off = (off + b + 255) & ~(size_t)255; return r; };
  size_t o_meta = walloc(4096);
  size_t o_bm1  = walloc(1024 * 4);
  size_t o_bm2  = walloc(256 * 8);
  size_t o_bmc  = walloc(64 * 4);
  size_t o_t2i  = walloc((size_t)NTOK * 2 * 4);
  size_t o_t2w  = walloc((size_t)NTOK * 2 * 4);
  size_t o_t2r  = walloc((size_t)NTOK * 2 * 4);
  size_t o_tok  = walloc((size_t)ROWS_CAP * 4);
  size_t o_xbf  = walloc((size_t)NTOK * DIM * 2);
  size_t o_y    = walloc((size_t)ROWS_CAP * DIM * 4);
  size_t o_w1p  = walloc((size_t)1024 * 16 * 8192);   // 128 MB
  size_t o_w2p  = walloc((size_t)256 * 64 * 8192);    // 128 MB
  size_t o_cwp  = walloc((size_t)256 * 8192);         // 2 MB
  size_t o_hc   = walloc((size_t)ROWS_CAP * HC * 2);  // 80 MB (L3-resident)

  int*                meta = (int*)(ws + o_meta);
  unsigned int*       bm1  = (unsigned int*)(ws + o_bm1);
  unsigned long long* bm2  = (unsigned long long*)(ws + o_bm2);
  unsigned int*       bmc  = (unsigned int*)(ws + o_bmc);
  int*                t2i  = (int*)(ws + o_t2i);
  float*              t2w  = (float*)(ws + o_t2w);
  int*                t2r  = (int*)(ws + o_t2r);
  int*                tok  = (int*)(ws + o_tok);
  unsigned short*     xbf  = (unsigned short*)(ws + o_xbf);
  float*              y    = (float*)(ws + o_y);
  unsigned short*     w1p  = (unsigned short*)(ws + o_w1p);
  unsigned short*     w2p  = (unsigned short*)(ws + o_w2p);
  unsigned short*     cwp  = (unsigned short*)(ws + o_cwp);
  unsigned short*     hc   = (unsigned short*)(ws + o_hc);

  hipMemsetAsync(ws + o_meta, 0, 4096, stream);
  hipMemsetAsync(ws + o_tok, 0xFF, (size_t)ROWS_CAP * 4, stream);  // -1

  k_detect <<<64, 256, 0, stream>>>((const unsigned int*)mask1, meta);
  k_bmask  <<<4, 256, 0, stream>>>(mask1, mask2, cmask, meta, bm1, bm2, bmc);
  k_wcast  <<<2064, 256, 0, stream>>>(w1, w2, cw, bm1, bm2, bmc, w1p, w2p, cwp);
  k_route  <<<NTOK / 4, 256, 0, stream>>>(x, gate_w + (size_t)1 * NEXP * DIM, temp + 1, t2i, t2w, meta);
  k_offsets<<<1, 64, 0, stream>>>(meta);
  k_assign <<<NTOK / 256, 256, 0, stream>>>(t2i, t2w, meta, tok, t2r);
  k_xcast  <<<(NTOK * DIM / 8) / 256, 256, 0, stream>>>(x, xbf);

  const int NRT = ROWS_CAP / BM;   // 160
  for (int c0 = 0; c0 < HID; c0 += HC) {
    k_gemm1<<<NRT * (HC / 64), 256, 0, stream>>>(xbf, w1p, b1, bm1, meta, tok, hc, c0);
    k_gemm2<<<NRT * 16, 256, 0, stream>>>(hc, w2p, b2, bm2, meta, y, c0);
  }
  k_cross<<<(NTOK / BM) * 16, 256, 0, stream>>>(y, x, cwp, cb, bmc, t2r, t2w, out);
}

// Round 6
// 500.763 us; speedup vs baseline: 1.2032x; 1.2032x over previous
//
#include <hip/hip_runtime.h>

// ---------------------------------------------------------------------------
// HierarchicalSparseLayer: top-2 MoE with block-sparse (64x64) masked weights
// B=8192 tokens, D=1024, H=4096, E=16 experts, K=2, + block-sparse cross proj.
// R6: revert to R3 core (best measured: BM=256/BN=64, A via global_load_lds
//     dbuf, B reg-staged f32 issue-early/write-late, 1 barrier/iter), plus:
//     no wcast, single K-pass, XCD-aware block swizzle (T1), expert_of_rt
//     table for a 2-load prologue.
// ---------------------------------------------------------------------------

#define NTOK 8192
#define DIM  1024
#define HID  4096
#define NEXP 16
#define BM   256
#define ROWS_CAP (NTOK*2 + NEXP*256)   // 20480

typedef __attribute__((ext_vector_type(4))) float fx4;
typedef __attribute__((ext_vector_type(4))) unsigned int ux4;
typedef __attribute__((ext_vector_type(2))) unsigned int ux2;
typedef __attribute__((ext_vector_type(8))) short s8v;
union V16 { ux4 u; s8v s; };

__device__ __forceinline__ unsigned int f2bf(float f) {
  unsigned int u = __float_as_uint(f);
  return (u + 0x7fffu + ((u >> 16) & 1u)) >> 16;   // RNE, inputs finite
}

__device__ __forceinline__ unsigned int cvt_pk(float lo, float hi) {
  unsigned int r;
  asm("v_cvt_pk_bf16_f32 %0, %1, %2" : "=v"(r) : "v"(lo), "v"(hi));
  return r;
}

// Mask dtype detected at runtime: flag 0=u8, 1=i32, 2=f32
__device__ __forceinline__ bool mask_at(const void* m, int flag, size_t idx) {
  if (flag == 0) return ((const unsigned char*)m)[idx] != 0;
  if (flag == 1) return ((const int*)m)[idx] != 0;
  return ((const float*)m)[idx] != 0.0f;
}

__device__ __forceinline__ int flag_of(int ev) {
  return (ev & 2) ? 2 : ((ev & 1) ? 0 : 1);
}

// XCD-aware swizzle: blocks with equal (orig%8) share an XCD; make them a
// contiguous logical range so panel re-reads stay in one XCD's L2.
__device__ __forceinline__ int xcd_swz() {
  const int b = blockIdx.x, cpx = gridDim.x >> 3;   // grid % 8 == 0
  return (b & 7) * cpx + (b >> 3);
}

// --------------------------- mask dtype detection ---------------------------
__global__ void k_detect(const unsigned int* __restrict__ m, int* __restrict__ meta) {
  int bits = 0;
  size_t base = (size_t)blockIdx.x * 4096 + threadIdx.x;
  for (int j = 0; j < 16; j++) {
    unsigned int v = m[base + 256 * j];
    if (v == 0x3f800000u) bits |= 2;
    else if (v > 1u)      bits |= 1;
  }
  if (bits) atomicOr(&meta[1], bits);
}

// --------------------------- routing ---------------------------------------
// meta: [1]=detect bits [8..23]=counts [32..47]=offsets [48]=total
//       [64..79]=slot counters [96..175]=expert_of_rt
__global__ void k_route(const float* __restrict__ x,
                        const float* __restrict__ gw,    // gate_w[-1] [16,1024]
                        const float* __restrict__ temp,
                        int* __restrict__ top2i, float* __restrict__ top2w,
                        int* __restrict__ meta)
{
  __shared__ float gwsh[NEXP * DIM];
  for (int i = threadIdx.x; i < NEXP * DIM; i += 256) gwsh[i] = gw[i];
  __syncthreads();

  const int t = blockIdx.x * 4 + (threadIdx.x >> 6);
  const int l = threadIdx.x & 63;
  const float* xr = x + (size_t)t * DIM;
  float xv[16];
  #pragma unroll
  for (int j = 0; j < 16; j++) xv[j] = xr[l + 64 * j];
  float logit[16];
  #pragma unroll
  for (int e = 0; e < 16; e++) {
    const float* g = gwsh + e * DIM;
    float s = 0.f;
    #pragma unroll
    for (int j = 0; j < 16; j++) s += xv[j] * g[l + 64 * j];
    #pragma unroll
    for (int o = 32; o >= 1; o >>= 1) s += __shfl_xor(s, o);
    logit[e] = s;
  }
  if (l == 0) {
    const float tinv = 1.0f / temp[0];
    int i0 = 0; float v0 = logit[0] * tinv;
    #pragma unroll
    for (int e = 1; e < 16; e++) { float v = logit[e] * tinv; if (v > v0) { v0 = v; i0 = e; } }
    int i1 = -1; float v1 = 0.f; bool first = true;
    #pragma unroll
    for (int e = 0; e < 16; e++) {
      if (e == i0) continue;
      float v = logit[e] * tinv;
      if (first || v > v1) { v1 = v; i1 = e; first = false; }
    }
    float ex = expf(v1 - v0);
    float den = 1.0f + ex;
    top2i[2 * t] = i0; top2i[2 * t + 1] = i1;
    top2w[2 * t] = 1.0f / den; top2w[2 * t + 1] = ex / den;
    atomicAdd(&meta[8 + i0], 1);
    atomicAdd(&meta[8 + i1], 1);
  }
}

__global__ void k_offsets(int* __restrict__ meta) {
  if (threadIdx.x == 0 && blockIdx.x == 0) {
    int o = 0;
    for (int e = 0; e < 16; e++) { meta[32 + e] = o; o += (meta[8 + e] + 255) & ~255; }
    meta[48] = o;
    for (int rt = 0; rt < ROWS_CAP / BM; rt++) {
      const int base = rt * BM;
      int e = 0;
      for (int i = 1; i < 16; i++) if (meta[32 + i] <= base) e = i;
      meta[96 + rt] = e;
    }
  }
}

__global__ void k_assign(const int* __restrict__ top2i,
                         const float* __restrict__ top2w,
                         int* __restrict__ meta, int* __restrict__ tok_of_row,
                         int* __restrict__ t2row)
{
  int t = blockIdx.x * 256 + threadIdx.x;
  if (t >= NTOK) return;
  #pragma unroll
  for (int k = 0; k < 2; k++) {
    int e = top2i[2 * t + k];
    int slot = atomicAdd(&meta[64 + e], 1);
    int row = meta[32 + e] + slot;
    tok_of_row[row] = t;
    t2row[2 * t + k] = row;
  }
}

// --------------------------- block-mask bitmaps ------------------------------
__global__ void k_bmask(const void* __restrict__ m1, const void* __restrict__ m2,
                        const void* __restrict__ mc, const int* __restrict__ meta,
                        unsigned int* __restrict__ bm1,
                        unsigned long long* __restrict__ bm2,
                        unsigned int* __restrict__ bmc)
{
  const int flag = flag_of(meta[1]);
  const int id = blockIdx.x * 256 + threadIdx.x;
  if (id < 1024) {
    int e = id >> 6, ct = id & 63;
    unsigned int bits = 0;
    size_t basei = (size_t)e * DIM * HID + (size_t)ct * 64;
    for (int db = 0; db < 16; db++)
      if (mask_at(m1, flag, basei + (size_t)db * 64 * HID)) bits |= 1u << db;
    bm1[id] = bits;
  }
  if (id < 256) {
    int e = id >> 4, ct = id & 15;
    unsigned long long bits = 0;
    size_t basei = (size_t)e * HID * DIM + (size_t)ct * 64;
    for (int db = 0; db < 64; db++)
      if (mask_at(m2, flag, basei + (size_t)db * 64 * DIM)) bits |= 1ull << db;
    bm2[id] = bits;
  }
  if (id < 16) {
    unsigned int bits = 0;
    for (int db = 0; db < 16; db++)
      if (mask_at(mc, flag, (size_t)db * 64 * DIM + (size_t)id * 64)) bits |= 1u << db;
    bmc[id] = bits;
  }
}

__global__ void k_xcast(const float* __restrict__ x, unsigned short* __restrict__ xb) {
  int i = blockIdx.x * 256 + threadIdx.x;
  const fx4* s = (const fx4*)x + (size_t)i * 2;
  fx4 a = s[0], b = s[1];
  ux4 o;
  o[0] = cvt_pk(a[0], a[1]);
  o[1] = cvt_pk(a[2], a[3]);
  o[2] = cvt_pk(b[0], b[1]);
  o[3] = cvt_pk(b[2], b[3]);
  ((ux4*)xb)[i] = o;
}

// --------------------------- GEMM 1: h = silu(x @ w1m + b1) -----------------
// BM=256 x BN=64, dbuf; A via global_load_lds (pre-swizzled source), B f32
// reg-staged: loads issued BEFORE compute, ds_write after (T14 overlap).
__global__ __launch_bounds__(256, 2)
void k_gemm1(const unsigned short* __restrict__ xb,
             const float* __restrict__ w1, const float* __restrict__ b1,
             const unsigned int* __restrict__ bm1,
             const int* __restrict__ meta, const int* __restrict__ tok_of_row,
             unsigned short* __restrict__ h_c)
{
  __shared__ ux4 Ash[2][2048];                  // 2 x 32 KB (256 rows x 64 k)
  __shared__ __align__(16) ux2 Bsh[2][1024];    // 2 x 8 KB

  const int bid = xcd_swz();
  const int rt = bid >> 6, ct = bid & 63;       // NCT = 64
  const int base = rt * BM;
  if (base >= meta[48]) return;
  const int e = meta[96 + rt];

  const int tid = threadIdx.x;
  const int wv = tid >> 6;
  const int jg0 = ct * 64;
  unsigned int bits = bm1[e * 64 + ct];

  const unsigned int sseg = (unsigned int)(((tid & 7) ^ ((tid >> 3) & 7)) * 16);
  unsigned int aoff[8];
  #pragma unroll
  for (int i = 0; i < 8; i++) {
    int tok = tok_of_row[base + i * 32 + (tid >> 3)];
    if (tok < 0) tok = 0;                       // pad rows: finite garbage, unused
    aoff[i] = (unsigned int)tok * (DIM * 2) + sseg;
  }

  const int l = tid & 63, l16 = l & 15, lhi = l >> 4;
  const int kb = tid >> 4, jb = tid & 15;

  fx4 acc[4][4] = {};

  auto STAGE_A = [&](int b, int d0) {
    const char* gp = (const char*)xb + (d0 << 1);
    #pragma unroll
    for (int i = 0; i < 8; i++)
      __builtin_amdgcn_global_load_lds(
        (const __attribute__((address_space(1))) unsigned int*)(gp + aoff[i]),
        (__attribute__((address_space(3))) unsigned int*)&Ash[b][i * 256 + wv * 64],
        16, 0, 0);
  };
  auto LOAD_B = [&](fx4* r, int d0) {
    const float* bp = w1 + ((size_t)e * DIM + d0 + kb * 4) * HID + jg0 + jb * 4;
    r[0] = *(const fx4*)bp;
    r[1] = *(const fx4*)(bp + HID);
    r[2] = *(const fx4*)(bp + 2 * HID);
    r[3] = *(const fx4*)(bp + 3 * HID);
  };
  auto WRITE_B = [&](int b, const fx4* r) {
    #pragma unroll
    for (int jj = 0; jj < 4; jj++) {
      ux2 val;
      val[0] = cvt_pk(r[0][jj], r[1][jj]);
      val[1] = cvt_pk(r[2][jj], r[3][jj]);
      const int col = jb * 4 + jj;
      Bsh[b][(col * 8 + ((kb >> 1) ^ (col & 7))) * 2 + (kb & 1)] = val;
    }
  };
  auto COMPUTE = [&](int b) {
    #pragma unroll
    for (int ks = 0; ks < 2; ks++) {
      s8v a[4], bb[4];
      const int seg = ks * 4 + lhi;
      #pragma unroll
      for (int m = 0; m < 4; m++) {
        const int row = wv * 64 + m * 16 + l16;
        V16 v; v.u = Ash[b][row * 8 + (seg ^ (row & 7))]; a[m] = v.s;
      }
      #pragma unroll
      for (int n = 0; n < 4; n++) {
        const int col = n * 16 + l16;
        V16 v; v.u = ((const ux4*)&Bsh[b][0])[col * 8 + (seg ^ (col & 7))]; bb[n] = v.s;
      }
      #pragma unroll
      for (int m = 0; m < 4; m++)
        #pragma unroll
        for (int n = 0; n < 4; n++)
          acc[m][n] = __builtin_amdgcn_mfma_f32_16x16x32_bf16(a[m], bb[n], acc[m][n], 0, 0, 0);
    }
  };

  if (bits) {
    int d0 = (__ffs(bits) - 1) << 6; bits &= bits - 1;
    {
      fx4 br[4];
      STAGE_A(0, d0);
      LOAD_B(br, d0);
      WRITE_B(0, br);
    }
    __syncthreads();
    int cur = 0;
    for (;;) {
      int nd0 = -1;
      fx4 br2[4];
      if (bits) { nd0 = (__ffs(bits) - 1) << 6; bits &= bits - 1; }
      if (nd0 >= 0) { STAGE_A(cur ^ 1, nd0); LOAD_B(br2, nd0); }
      COMPUTE(cur);
      if (nd0 >= 0) WRITE_B(cur ^ 1, br2);
      __syncthreads();
      cur ^= 1;
      if (nd0 < 0) break;
    }
  }

  // epilogue: silu(acc + b1) -> LDS bf16 tile -> coalesced 16B dump
  unsigned short* hs = (unsigned short*)&Ash[0][0];
  __syncthreads();
  #pragma unroll
  for (int m = 0; m < 4; m++)
    #pragma unroll
    for (int n = 0; n < 4; n++) {
      const int gcol = jg0 + n * 16 + l16;
      const float bbv = b1[e * HID + gcol];
      #pragma unroll
      for (int i = 0; i < 4; i++) {
        const int row = wv * 64 + m * 16 + lhi * 4 + i;
        float v = acc[m][n][i] + bbv;
        float hval = v / (1.0f + expf(-v));
        hs[row * 64 + n * 16 + l16] = (unsigned short)f2bf(hval);
      }
    }
  __syncthreads();
  {
    const ux4* s = (const ux4*)hs;
    #pragma unroll
    for (int j = 0; j < 8; j++) {
      const int c2 = j * 256 + tid;
      const int row = c2 >> 3;
      *(ux4*)(h_c + (size_t)(base + row) * HID + ct * 64 + (c2 & 7) * 8) = s[c2];
    }
  }
}

// --------------------------- GEMM 2: y = h @ w2m + b2 (pair rows) -----------
__global__ __launch_bounds__(256, 2)
void k_gemm2(const unsigned short* __restrict__ h_c,
             const float* __restrict__ w2, const float* __restrict__ b2,
             const unsigned long long* __restrict__ bm2,
             const int* __restrict__ meta, float* __restrict__ y)
{
  __shared__ ux4 Ash[2][2048];
  __shared__ __align__(16) ux2 Bsh[2][1024];

  const int bid = xcd_swz();
  const int rt = bid >> 4, ct = bid & 15;       // NCT = 16
  const int base = rt * BM;
  if (base >= meta[48]) return;
  const int e = meta[96 + rt];

  const int tid = threadIdx.x;
  const int wv = tid >> 6;
  const int jg0 = ct * 64;
  unsigned long long bits = bm2[e * 16 + ct];

  const unsigned int sseg = (unsigned int)(((tid & 7) ^ ((tid >> 3) & 7)) * 16);
  unsigned int aoff[8];
  #pragma unroll
  for (int i = 0; i < 8; i++)
    aoff[i] = (unsigned int)(base + i * 32 + (tid >> 3)) * (unsigned int)(HID * 2) + sseg;

  const int l = tid & 63, l16 = l & 15, lhi = l >> 4;
  const int kb = tid >> 4, jb = tid & 15;

  fx4 acc[4][4] = {};

  auto STAGE_A = [&](int b, int d0) {
    const char* gp = (const char*)h_c + (d0 << 1);
    #pragma unroll
    for (int i = 0; i < 8; i++)
      __builtin_amdgcn_global_load_lds(
        (const __attribute__((address_space(1))) unsigned int*)(gp + aoff[i]),
        (__attribute__((address_space(3))) unsigned int*)&Ash[b][i * 256 + wv * 64],
        16, 0, 0);
  };
  auto LOAD_B = [&](fx4* r, int d0) {
    const float* bp = w2 + ((size_t)e * HID + d0 + kb * 4) * DIM + jg0 + jb * 4;
    r[0] = *(const fx4*)bp;
    r[1] = *(const fx4*)(bp + DIM);
    r[2] = *(const fx4*)(bp + 2 * DIM);
    r[3] = *(const fx4*)(bp + 3 * DIM);
  };
  auto WRITE_B = [&](int b, const fx4* r) {
    #pragma unroll
    for (int jj = 0; jj < 4; jj++) {
      ux2 val;
      val[0] = cvt_pk(r[0][jj], r[1][jj]);
      val[1] = cvt_pk(r[2][jj], r[3][jj]);
      const int col = jb * 4 + jj;
      Bsh[b][(col * 8 + ((kb >> 1) ^ (col & 7))) * 2 + (kb & 1)] = val;
    }
  };
  auto COMPUTE = [&](int b) {
    #pragma unroll
    for (int ks = 0; ks < 2; ks++) {
      s8v a[4], bb[4];
      const int seg = ks * 4 + lhi;
      #pragma unroll
      for (int m = 0; m < 4; m++) {
        const int row = wv * 64 + m * 16 + l16;
        V16 v; v.u = Ash[b][row * 8 + (seg ^ (row & 7))]; a[m] = v.s;
      }
      #pragma unroll
      for (int n = 0; n < 4; n++) {
        const int col = n * 16 + l16;
        V16 v; v.u = ((const ux4*)&Bsh[b][0])[col * 8 + (seg ^ (col & 7))]; bb[n] = v.s;
      }
      #pragma unroll
      for (int m = 0; m < 4; m++)
        #pragma unroll
        for (int n = 0; n < 4; n++)
          acc[m][n] = __builtin_amdgcn_mfma_f32_16x16x32_bf16(a[m], bb[n], acc[m][n], 0, 0, 0);
    }
  };

  if (bits) {
    int d0 = (__ffsll(bits) - 1) << 6; bits &= bits - 1;
    {
      fx4 br[4];
      STAGE_A(0, d0);
      LOAD_B(br, d0);
      WRITE_B(0, br);
    }
    __syncthreads();
    int cur = 0;
    for (;;) {
      int nd0 = -1;
      fx4 br2[4];
      if (bits) { nd0 = (__ffsll(bits) - 1) << 6; bits &= bits - 1; }
      if (nd0 >= 0) { STAGE_A(cur ^ 1, nd0); LOAD_B(br2, nd0); }
      COMPUTE(cur);
      if (nd0 >= 0) WRITE_B(cur ^ 1, br2);
      __syncthreads();
      cur ^= 1;
      if (nd0 < 0) break;
    }
  }

  // epilogue: y = acc + b2 (single K-pass)
  #pragma unroll
  for (int m = 0; m < 4; m++)
    #pragma unroll
    for (int n = 0; n < 4; n++) {
      const int gcol = jg0 + n * 16 + l16;
      const float bbv = b2[e * DIM + gcol];
      #pragma unroll
      for (int i = 0; i < 4; i++) {
        const int lrow = wv * 64 + m * 16 + lhi * 4 + i;
        y[(size_t)(base + lrow) * DIM + gcol] = acc[m][n][i] + bbv;
      }
    }
}

// --------------------------- cross: out = x + eo @ cwm + cb -----------------
// eo rows formed on the fly: eo[tok] = w0*y[r0] + w1*y[r1]
__global__ __launch_bounds__(256, 2)
void k_cross(const float* __restrict__ y, const float* __restrict__ x,
             const float* __restrict__ cw, const float* __restrict__ cb,
             const unsigned int* __restrict__ bmc,
             const int* __restrict__ t2row, const float* __restrict__ t2w,
             float* __restrict__ out)
{
  __shared__ ux4 Ash[2048];
  __shared__ __align__(16) ux2 Bsh[1024];

  const int bid = xcd_swz();
  const int rt = bid >> 4, ct = bid & 15;
  const int base = rt * BM;
  const int tid = threadIdx.x;
  const int jg0 = ct * 64;

  const int tok = base + tid;
  const int r0 = t2row[2 * tok], r1 = t2row[2 * tok + 1];
  const float w0 = t2w[2 * tok], w1 = t2w[2 * tok + 1];

  fx4 acc[4][4] = {};
  const int wave = tid >> 6, l = tid & 63;
  const int l16 = l & 15, lhi = l >> 4;

  unsigned int bits = bmc[ct];
  while (bits) {
    const int kb = __ffs(bits) - 1; bits &= bits - 1;
    const int d0 = kb * 64;
    {   // stage A: combine two pair rows -> bf16 (swizzled ds_write)
      const fx4* s0 = (const fx4*)(y + (size_t)r0 * DIM + d0);
      const fx4* s1 = (const fx4*)(y + (size_t)r1 * DIM + d0);
      #pragma unroll
      for (int seg = 0; seg < 8; seg++) {
        fx4 p = w0 * s0[seg * 2]     + w1 * s1[seg * 2];
        fx4 q = w0 * s0[seg * 2 + 1] + w1 * s1[seg * 2 + 1];
        ux4 v;
        v[0] = cvt_pk(p[0], p[1]);
        v[1] = cvt_pk(p[2], p[3]);
        v[2] = cvt_pk(q[0], q[1]);
        v[3] = cvt_pk(q[2], q[3]);
        Ash[tid * 8 + (seg ^ (tid & 7))] = v;
      }
    }
    {   // stage B from cross_w (f32 reg-staged)
      const int kbt = tid >> 4, jb = tid & 15;
      const float* bp = cw + (size_t)(d0 + kbt * 4) * DIM + jg0 + jb * 4;
      fx4 r0v = *(const fx4*)bp;
      fx4 r1v = *(const fx4*)(bp + DIM);
      fx4 r2v = *(const fx4*)(bp + 2 * DIM);
      fx4 r3v = *(const fx4*)(bp + 3 * DIM);
      #pragma unroll
      for (int jj = 0; jj < 4; jj++) {
        ux2 val;
        val[0] = cvt_pk(r0v[jj], r1v[jj]);
        val[1] = cvt_pk(r2v[jj], r3v[jj]);
        const int col = jb * 4 + jj;
        Bsh[(col * 8 + ((kbt >> 1) ^ (col & 7))) * 2 + (kbt & 1)] = val;
      }
    }
    __syncthreads();
    #pragma unroll
    for (int ks = 0; ks < 2; ks++) {
      s8v a[4], b[4];
      const int seg = ks * 4 + lhi;
      #pragma unroll
      for (int m = 0; m < 4; m++) {
        const int row = wave * 64 + m * 16 + l16;
        V16 v; v.u = Ash[row * 8 + (seg ^ (row & 7))]; a[m] = v.s;
      }
      #pragma unroll
      for (int n = 0; n < 4; n++) {
        const int col = n * 16 + l16;
        V16 v; v.u = ((const ux4*)Bsh)[col * 8 + (seg ^ (col & 7))]; b[n] = v.s;
      }
      #pragma unroll
      for (int m = 0; m < 4; m++)
        #pragma unroll
        for (int n = 0; n < 4; n++)
          acc[m][n] = __builtin_amdgcn_mfma_f32_16x16x32_bf16(a[m], b[n], acc[m][n], 0, 0, 0);
    }
    __syncthreads();
  }

  #pragma unroll
  for (int m = 0; m < 4; m++)
    #pragma unroll
    for (int n = 0; n < 4; n++) {
      const int gcol = jg0 + n * 16 + l16;
      #pragma unroll
      for (int i = 0; i < 4; i++) {
        const int lrow = wave * 64 + m * 16 + lhi * 4 + i;
        const size_t idx = (size_t)(base + lrow) * DIM + gcol;
        out[idx] = acc[m][n][i] + x[idx] + cb[gcol];
      }
    }
}

// ---------------------------------------------------------------------------
extern "C" void kernel_launch(void* const* d_in, const int* in_sizes, int n_in,
                              void* d_out, int out_size, void* d_ws, size_t ws_size,
                              hipStream_t stream)
{
  (void)in_sizes; (void)n_in; (void)out_size; (void)ws_size;
  const float* x      = (const float*)d_in[0];
  const float* gate_w = (const float*)d_in[1];   // [2,16,1024]
  const float* temp   = (const float*)d_in[2];   // [2]
  const float* w1     = (const float*)d_in[3];   // [16,1024,4096]
  const float* b1     = (const float*)d_in[4];
  const float* w2     = (const float*)d_in[5];   // [16,4096,1024]
  const float* b2     = (const float*)d_in[6];
  const float* cw     = (const float*)d_in[7];   // [1024,1024]
  const float* cb     = (const float*)d_in[8];
  const void*  mask1  = d_in[9];
  const void*  mask2  = d_in[10];
  const void*  cmask  = d_in[11];
  float* out = (float*)d_out;
  char* ws = (char*)d_ws;

  size_t off = 0;
  auto walloc = [&](size_t b) { size_t r = off; off = (off + b + 255) & ~(size_t)255; return r; };
  size_t o_meta = walloc(4096);
  size_t o_bm1  = walloc(1024 * 4);
  size_t o_bm2  = walloc(256 * 8);
  size_t o_bmc  = walloc(64 * 4);
  size_t o_t2i  = walloc((size_t)NTOK * 2 * 4);
  size_t o_t2w  = walloc((size_t)NTOK * 2 * 4);
  size_t o_t2r  = walloc((size_t)NTOK * 2 * 4);
  size_t o_tok  = walloc((size_t)ROWS_CAP * 4);
  size_t o_xbf  = walloc((size_t)NTOK * DIM * 2);
  size_t o_y    = walloc((size_t)ROWS_CAP * DIM * 4);    // 80 MB
  size_t o_hc   = walloc((size_t)ROWS_CAP * HID * 2);    // 168 MB

  int*                meta = (int*)(ws + o_meta);
  unsigned int*       bm1  = (unsigned int*)(ws + o_bm1);
  unsigned long long* bm2  = (unsigned long long*)(ws + o_bm2);
  unsigned int*       bmc  = (unsigned int*)(ws + o_bmc);
  int*                t2i  = (int*)(ws + o_t2i);
  float*              t2w  = (float*)(ws + o_t2w);
  int*                t2r  = (int*)(ws + o_t2r);
  int*                tok  = (int*)(ws + o_tok);
  unsigned short*     xbf  = (unsigned short*)(ws + o_xbf);
  float*              y    = (float*)(ws + o_y);
  unsigned short*     hc   = (unsigned short*)(ws + o_hc);

  hipMemsetAsync(ws + o_meta, 0, 4096, stream);
  hipMemsetAsync(ws + o_tok, 0xFF, (size_t)ROWS_CAP * 4, stream);  // -1

  k_detect <<<64, 256, 0, stream>>>((const unsigned int*)mask1, meta);
  k_bmask  <<<4, 256, 0, stream>>>(mask1, mask2, cmask, meta, bm1, bm2, bmc);
  k_route  <<<NTOK / 4, 256, 0, stream>>>(x, gate_w + (size_t)1 * NEXP * DIM, temp + 1, t2i, t2w, meta);
  k_offsets<<<1, 64, 0, stream>>>(meta);
  k_assign <<<NTOK / 256, 256, 0, stream>>>(t2i, t2w, meta, tok, t2r);
  k_xcast  <<<(NTOK * DIM / 8) / 256, 256, 0, stream>>>(x, xbf);

  const int NRT = ROWS_CAP / BM;   // 80
  k_gemm1<<<NRT * 64, 256, 0, stream>>>(xbf, w1, b1, bm1, meta, tok, hc);
  k_gemm2<<<NRT * 16, 256, 0, stream>>>(hc, w2, b2, bm2, meta, y);
  k_cross<<<(NTOK / BM) * 16, 256, 0, stream>>>(y, x, cw, cb, bmc, t2r, t2w, out);
}